// Round 2
// baseline (5609.253 us; speedup 1.0000x reference)
//
#include <hip/hip_runtime.h>
#include <hip/hip_bf16.h>

typedef __hip_bfloat16 bf16;

// ---- problem constants (from reference) ----
#define N0 400000
#define N1 120000
#define N2 20000
#define N3 4000
#define E0 1800000
#define E1 200000
#define E2 20000
#define D_IN 128
#define D_HID 256
#define D_OUT 47

__device__ __forceinline__ float ldv(const float* p) { return *p; }
__device__ __forceinline__ float ldv(const bf16* p) { return __bfloat162float(*p); }
__device__ __forceinline__ void stv(float* p, float v) { *p = v; }
__device__ __forceinline__ void stv(bf16* p, float v) { *p = __float2bfloat16(v); }

// ------------------- degree count -------------------
__global__ void deg_count(const int* __restrict__ dst, int E, float* __restrict__ deg) {
    int i = blockIdx.x * blockDim.x + threadIdx.x;
    if (i < E) atomicAdd(&deg[dst[i]], 1.0f);
}

// ------------------- scatter-add gather, f32 source, 4 feats/thread -------------------
__global__ void scatter_f32(const float* __restrict__ h, const int* __restrict__ src,
                            const int* __restrict__ dst, int E, int logd,
                            float* __restrict__ agg) {
    int din = 1 << logd;
    int per = din >> 2;  // float4 groups per edge
    long long total = (long long)E * per;
    long long idx = (long long)blockIdx.x * blockDim.x + threadIdx.x;
    if (idx >= total) return;
    int e = (int)(idx >> (logd - 2));
    int f4 = (int)(idx & (per - 1)) << 2;
    int s = src[e];
    int d = dst[e];
    float4 v = *(const float4*)(h + (size_t)s * din + f4);
    float* a = agg + (size_t)d * din + f4;
    atomicAdd(a + 0, v.x);
    atomicAdd(a + 1, v.y);
    atomicAdd(a + 2, v.z);
    atomicAdd(a + 3, v.w);
}

// ------------------- scatter-add gather, bf16 source, 8 feats/thread -------------------
__global__ void scatter_bf16(const bf16* __restrict__ h, const int* __restrict__ src,
                             const int* __restrict__ dst, int E, int logd,
                             float* __restrict__ agg) {
    int din = 1 << logd;
    int per = din >> 3;  // 8-elem groups per edge
    long long total = (long long)E * per;
    long long idx = (long long)blockIdx.x * blockDim.x + threadIdx.x;
    if (idx >= total) return;
    int e = (int)(idx >> (logd - 3));
    int f8 = (int)(idx & (per - 1)) << 3;
    int s = src[e];
    int d = dst[e];
    union { uint4 u; unsigned short us[8]; } r;
    r.u = *(const uint4*)(h + (size_t)s * din + f8);
    float* a = agg + (size_t)d * din + f8;
    #pragma unroll
    for (int j = 0; j < 8; j++) {
        float v = __uint_as_float(((unsigned)r.us[j]) << 16);
        atomicAdd(a + j, v);
    }
}

// ------------------- in-place mean normalize -------------------
__global__ void normalize_mean(float* __restrict__ agg, const float* __restrict__ deg,
                               long long total, int logd) {
    long long i = (long long)blockIdx.x * blockDim.x + threadIdx.x;
    if (i < total) {
        float d = deg[i >> logd];
        agg[i] = agg[i] / fmaxf(d, 1.0f);
    }
}

// ------------------- fused SAGE GEMM -------------------
// C[M,N] = relu?( A[M,K]@Ws[K,N] + Mn[M,K]@Wn[K,N] + b[N] ), all f32 math.
template <typename TA, typename TC, bool RELU>
__global__ __launch_bounds__(256) void gemm_fused(
    const TA* __restrict__ A, const float* __restrict__ Mn,
    const float* __restrict__ Ws, const float* __restrict__ Wn,
    const float* __restrict__ bias, TC* __restrict__ C,
    int M, int N, int K) {
    const int BM = 64, BN = 64, BK = 16;
    __shared__ float As[BK][BM + 1];
    __shared__ float Am[BK][BM + 1];
    __shared__ float Bs[BK][BN + 1];
    __shared__ float Bn[BK][BN + 1];

    int m0 = blockIdx.x * BM;
    int n0 = blockIdx.y * BN;
    int tid = threadIdx.x;
    int tx = tid & 15, ty = tid >> 4;

    float acc[4][4] = {};

    for (int k0 = 0; k0 < K; k0 += BK) {
        #pragma unroll
        for (int i = 0; i < 4; i++) {
            int lin = tid * 4 + i;
            int m = lin >> 4;
            int k = lin & 15;
            int gm = m0 + m, gk = k0 + k;
            float a = 0.f, am = 0.f;
            if (gm < M) {
                a  = ldv(&A[(size_t)gm * K + gk]);
                am = Mn[(size_t)gm * K + gk];
            }
            As[k][m] = a;
            Am[k][m] = am;
        }
        #pragma unroll
        for (int i = 0; i < 4; i++) {
            int lin = tid * 4 + i;
            int k = lin >> 6;
            int n = lin & 63;
            int gk = k0 + k, gn = n0 + n;
            float ws = 0.f, wn = 0.f;
            if (gn < N) {
                ws = Ws[(size_t)gk * N + gn];
                wn = Wn[(size_t)gk * N + gn];
            }
            Bs[k][n] = ws;
            Bn[k][n] = wn;
        }
        __syncthreads();
        #pragma unroll
        for (int k = 0; k < BK; k++) {
            float av[4], mv[4], bsv[4], bnv[4];
            #pragma unroll
            for (int i = 0; i < 4; i++) { av[i] = As[k][ty * 4 + i]; mv[i] = Am[k][ty * 4 + i]; }
            #pragma unroll
            for (int j = 0; j < 4; j++) { bsv[j] = Bs[k][tx * 4 + j]; bnv[j] = Bn[k][tx * 4 + j]; }
            #pragma unroll
            for (int i = 0; i < 4; i++)
                #pragma unroll
                for (int j = 0; j < 4; j++)
                    acc[i][j] += av[i] * bsv[j] + mv[i] * bnv[j];
        }
        __syncthreads();
    }

    #pragma unroll
    for (int i = 0; i < 4; i++) {
        int gm = m0 + ty * 4 + i;
        if (gm >= M) continue;
        #pragma unroll
        for (int j = 0; j < 4; j++) {
            int gn = n0 + tx * 4 + j;
            if (gn >= N) continue;
            float v = acc[i][j] + bias[gn];
            if (RELU) v = fmaxf(v, 0.f);
            stv(&C[(size_t)gm * N + gn], v);
        }
    }
}

// ------------------- launch -------------------
extern "C" void kernel_launch(void* const* d_in, const int* in_sizes, int n_in,
                              void* d_out, int out_size, void* d_ws, size_t ws_size,
                              hipStream_t stream) {
    const float* x    = (const float*)d_in[0];
    const int*  src0 = (const int*)d_in[1];
    const int*  dst0 = (const int*)d_in[2];
    const int*  src1 = (const int*)d_in[3];
    const int*  dst1 = (const int*)d_in[4];
    const int*  src2 = (const int*)d_in[5];
    const int*  dst2 = (const int*)d_in[6];
    const float* Ws0 = (const float*)d_in[7];
    const float* Wn0 = (const float*)d_in[8];
    const float* b0  = (const float*)d_in[9];
    const float* Ws1 = (const float*)d_in[10];
    const float* Wn1 = (const float*)d_in[11];
    const float* b1  = (const float*)d_in[12];
    const float* Ws2 = (const float*)d_in[13];
    const float* Wn2 = (const float*)d_in[14];
    const float* b2  = (const float*)d_in[15];
    float* out = (float*)d_out;

    char* ws = (char*)d_ws;
    // workspace layout (bytes); peak ~123.4 MB
    const size_t OFF_AGG0 = 0;           // f32 120000x128 = 61,440,000
    const size_t OFF_DEG0 = 61440000;    // f32 120000     =    480,000
    const size_t OFF_H1   = 61920000;    // bf16 120000x256 = 61,440,000 (end 123,360,000)
    const size_t OFF_AGG1 = 0;           // f32 20000x256  = 20,480,000 (reuse AGG0)
    const size_t OFF_DEG1 = 20480000;    // f32 20000      =     80,000
    const size_t OFF_H2   = 20560000;    // f32 20000x256  = 20,480,000 (end 41,040,000)
    const size_t OFF_AGG2 = 61920000;    // f32 4000x256   =  4,096,000 (reuse H1, dead after gemm1)
    const size_t OFF_DEG2 = 66016000;    // f32 4000       =     16,000

    float* agg0 = (float*)(ws + OFF_AGG0);
    float* deg0 = (float*)(ws + OFF_DEG0);
    bf16*  h1   = (bf16*)(ws + OFF_H1);
    float* agg1 = (float*)(ws + OFF_AGG1);
    float* deg1 = (float*)(ws + OFF_DEG1);
    float* h2   = (float*)(ws + OFF_H2);
    float* agg2 = (float*)(ws + OFF_AGG2);
    float* deg2 = (float*)(ws + OFF_DEG2);

    // ---------------- layer 0: 400000 -> 120000, K=128 -> 256, relu ----------------
    hipMemsetAsync(ws + OFF_AGG0, 0, 61440000 + 480000, stream);  // agg0 + deg0 contiguous
    deg_count<<<(E0 + 255) / 256, 256, 0, stream>>>(dst0, E0, deg0);
    {
        long long total = (long long)E0 * (D_IN / 4);
        scatter_f32<<<(int)((total + 255) / 256), 256, 0, stream>>>(x, src0, dst0, E0, 7, agg0);
        long long ntot = (long long)N1 * D_IN;
        normalize_mean<<<(int)((ntot + 255) / 256), 256, 0, stream>>>(agg0, deg0, ntot, 7);
    }
    {
        dim3 grid((N1 + 63) / 64, (D_HID + 63) / 64);
        gemm_fused<float, bf16, true><<<grid, 256, 0, stream>>>(x, agg0, Ws0, Wn0, b0, h1, N1, D_HID, D_IN);
    }

    // ---------------- layer 1: 120000 -> 20000, K=256 -> 256, relu ----------------
    hipMemsetAsync(ws + OFF_AGG1, 0, 20480000 + 80000, stream);  // agg1 + deg1 contiguous
    deg_count<<<(E1 + 255) / 256, 256, 0, stream>>>(dst1, E1, deg1);
    {
        long long total = (long long)E1 * (D_HID / 8);
        scatter_bf16<<<(int)((total + 255) / 256), 256, 0, stream>>>(h1, src1, dst1, E1, 8, agg1);
        long long ntot = (long long)N2 * D_HID;
        normalize_mean<<<(int)((ntot + 255) / 256), 256, 0, stream>>>(agg1, deg1, ntot, 8);
    }
    {
        dim3 grid((N2 + 63) / 64, (D_HID + 63) / 64);
        gemm_fused<bf16, float, true><<<grid, 256, 0, stream>>>(h1, agg1, Ws1, Wn1, b1, h2, N2, D_HID, D_HID);
    }

    // ---------------- layer 2: 20000 -> 4000, K=256 -> 47, no relu ----------------
    hipMemsetAsync(ws + OFF_AGG2, 0, 4096000, stream);
    hipMemsetAsync(ws + OFF_DEG2, 0, 16000, stream);
    deg_count<<<(E2 + 255) / 256, 256, 0, stream>>>(dst2, E2, deg2);
    {
        long long total = (long long)E2 * (D_HID / 4);
        scatter_f32<<<(int)((total + 255) / 256), 256, 0, stream>>>(h2, src2, dst2, E2, 8, agg2);
        long long ntot = (long long)N3 * D_HID;
        normalize_mean<<<(int)((ntot + 255) / 256), 256, 0, stream>>>(agg2, deg2, ntot, 8);
    }
    {
        dim3 grid((N3 + 63) / 64, (D_OUT + 63) / 64);
        gemm_fused<float, float, false><<<grid, 256, 0, stream>>>(h2, agg2, Ws2, Wn2, b2, out, N3, D_OUT, D_HID);
    }
}

// Round 3
// 1415.301 us; speedup vs baseline: 3.9633x; 3.9633x over previous
//
#include <hip/hip_runtime.h>
#include <hip/hip_bf16.h>

typedef __hip_bfloat16 bf16;

// ---- problem constants (from reference) ----
#define N0 400000
#define N1 120000
#define N2 20000
#define N3 4000
#define E0 1800000
#define E1 200000
#define E2 20000
#define D_IN 128
#define D_HID 256
#define D_OUT 47

__device__ __forceinline__ float ldv(const float* p) { return *p; }
__device__ __forceinline__ float ldv(const bf16* p) { return __bfloat162float(*p); }
__device__ __forceinline__ void stv(float* p, float v) { *p = v; }
__device__ __forceinline__ void stv(bf16* p, float v) { *p = __float2bfloat16(v); }

// ================= CSR build =================

__global__ void hist_count(const int* __restrict__ dst, int E, int* __restrict__ cnt) {
    int i = blockIdx.x * blockDim.x + threadIdx.x;
    if (i < E) atomicAdd(&cnt[dst[i]], 1);
}

// chunk = 1024 elems per block (256 thr x 4); exclusive scan within chunk
__global__ __launch_bounds__(256) void scan_chunk(const int* __restrict__ cnt, int n,
                                                  int* __restrict__ out, int* __restrict__ bsum) {
    __shared__ int sd[256];
    int b = blockIdx.x, t = threadIdx.x;
    int base = b * 1024 + t * 4;
    int v[4]; int s = 0;
    #pragma unroll
    for (int j = 0; j < 4; j++) { int i = base + j; v[j] = (i < n) ? cnt[i] : 0; s += v[j]; }
    sd[t] = s;
    __syncthreads();
    for (int off = 1; off < 256; off <<= 1) {
        int x = (t >= off) ? sd[t - off] : 0;
        __syncthreads();
        sd[t] += x;
        __syncthreads();
    }
    int excl = sd[t] - s;  // exclusive prefix of this thread's 4-group
    int run = excl;
    #pragma unroll
    for (int j = 0; j < 4; j++) { int i = base + j; if (i < n) out[i] = run; run += v[j]; }
    if (t == 255) bsum[b] = sd[255];
}

// scans up to 256 block sums (exclusive), writes grand total to *total
__global__ __launch_bounds__(256) void scan_bsum(int* __restrict__ bsum, int B, int* __restrict__ total) {
    __shared__ int sd[256];
    int t = threadIdx.x;
    int s = (t < B) ? bsum[t] : 0;
    sd[t] = s;
    __syncthreads();
    for (int off = 1; off < 256; off <<= 1) {
        int x = (t >= off) ? sd[t - off] : 0;
        __syncthreads();
        sd[t] += x;
        __syncthreads();
    }
    if (t < B) bsum[t] = sd[t] - s;
    if (t == 255) *total = sd[255];
}

__global__ void scan_add(int* __restrict__ out, int n, const int* __restrict__ bsum) {
    int i = blockIdx.x * blockDim.x + threadIdx.x;
    if (i < n) out[i] += bsum[i >> 10];
}

__global__ void copy_int(const int* __restrict__ a, int* __restrict__ b, int n) {
    int i = blockIdx.x * blockDim.x + threadIdx.x;
    if (i < n) b[i] = a[i];
}

__global__ void csr_fill(const int* __restrict__ src, const int* __restrict__ dst, int E,
                         int* __restrict__ cursor, int* __restrict__ col) {
    int e = blockIdx.x * blockDim.x + threadIdx.x;
    if (e < E) {
        int d = dst[e];
        int p = atomicAdd(&cursor[d], 1);
        col[p] = src[e];
    }
}

// ================= gather-mean aggregation =================
// one wave per dst node; lanes tile the feature dim.
template <int DIN, typename T>
__global__ __launch_bounds__(256) void gather_mean(const T* __restrict__ h,
        const int* __restrict__ row_ptr, const int* __restrict__ col,
        int n_dst, float* __restrict__ agg) {
    int gw = (blockIdx.x * blockDim.x + threadIdx.x) >> 6;
    int lane = threadIdx.x & 63;
    if (gw >= n_dst) return;
    int beg = row_ptr[gw], end = row_ptr[gw + 1];
    constexpr int VP = DIN / 64;  // elems per lane: 2 (f32 d128) or 4
    float s[VP] = {};

    auto accum = [&](int srcn) {
        const T* hp = h + (size_t)srcn * DIN + lane * VP;
        if constexpr (sizeof(T) == 4 && VP == 2) {
            float2 v = *(const float2*)hp;
            s[0] += v.x; s[1] += v.y;
        } else if constexpr (sizeof(T) == 4 && VP == 4) {
            float4 v = *(const float4*)hp;
            s[0] += v.x; s[1] += v.y; s[2] += v.z; s[3] += v.w;
        } else {  // bf16, VP==4 -> 8B load
            union { uint2 u; unsigned short us[4]; } r;
            r.u = *(const uint2*)hp;
            #pragma unroll
            for (int j = 0; j < 4; j++) s[j] += __uint_as_float(((unsigned)r.us[j]) << 16);
        }
    };

    int e = beg;
    for (; e + 1 < end; e += 2) {  // 2 edges in flight
        int s0 = col[e], s1 = col[e + 1];
        accum(s0);
        accum(s1);
    }
    if (e < end) accum(col[e]);

    float inv = 1.f / fmaxf((float)(end - beg), 1.f);
    #pragma unroll
    for (int j = 0; j < VP; j++) s[j] *= inv;

    float* ap = agg + (size_t)gw * DIN + lane * VP;
    if constexpr (VP == 2) {
        *(float2*)ap = make_float2(s[0], s[1]);
    } else {
        *(float4*)ap = make_float4(s[0], s[1], s[2], s[3]);
    }
}

// ================= fused SAGE GEMM =================
// C[M,N] = relu?( A[M,K]@Ws[K,N] + Mn[M,K]@Wn[K,N] + b[N] ), f32 math.
template <typename TA, typename TC, bool RELU>
__global__ __launch_bounds__(256) void gemm_fused(
    const TA* __restrict__ A, const float* __restrict__ Mn,
    const float* __restrict__ Ws, const float* __restrict__ Wn,
    const float* __restrict__ bias, TC* __restrict__ C,
    int M, int N, int K) {
    const int BM = 64, BN = 64, BK = 16;
    __shared__ float As[BK][BM + 1];
    __shared__ float Am[BK][BM + 1];
    __shared__ float Bs[BK][BN + 1];
    __shared__ float Bn[BK][BN + 1];

    int m0 = blockIdx.x * BM;
    int n0 = blockIdx.y * BN;
    int tid = threadIdx.x;
    int tx = tid & 15, ty = tid >> 4;

    float acc[4][4] = {};

    for (int k0 = 0; k0 < K; k0 += BK) {
        #pragma unroll
        for (int i = 0; i < 4; i++) {
            int lin = tid * 4 + i;
            int m = lin >> 4;
            int k = lin & 15;
            int gm = m0 + m, gk = k0 + k;
            float a = 0.f, am = 0.f;
            if (gm < M) {
                a  = ldv(&A[(size_t)gm * K + gk]);
                am = Mn[(size_t)gm * K + gk];
            }
            As[k][m] = a;
            Am[k][m] = am;
        }
        #pragma unroll
        for (int i = 0; i < 4; i++) {
            int lin = tid * 4 + i;
            int k = lin >> 6;
            int n = lin & 63;
            int gk = k0 + k, gn = n0 + n;
            float ws = 0.f, wn = 0.f;
            if (gn < N) {
                ws = Ws[(size_t)gk * N + gn];
                wn = Wn[(size_t)gk * N + gn];
            }
            Bs[k][n] = ws;
            Bn[k][n] = wn;
        }
        __syncthreads();
        #pragma unroll
        for (int k = 0; k < BK; k++) {
            float av[4], mv[4], bsv[4], bnv[4];
            #pragma unroll
            for (int i = 0; i < 4; i++) { av[i] = As[k][ty * 4 + i]; mv[i] = Am[k][ty * 4 + i]; }
            #pragma unroll
            for (int j = 0; j < 4; j++) { bsv[j] = Bs[k][tx * 4 + j]; bnv[j] = Bn[k][tx * 4 + j]; }
            #pragma unroll
            for (int i = 0; i < 4; i++)
                #pragma unroll
                for (int j = 0; j < 4; j++)
                    acc[i][j] += av[i] * bsv[j] + mv[i] * bnv[j];
        }
        __syncthreads();
    }

    #pragma unroll
    for (int i = 0; i < 4; i++) {
        int gm = m0 + ty * 4 + i;
        if (gm >= M) continue;
        #pragma unroll
        for (int j = 0; j < 4; j++) {
            int gn = n0 + tx * 4 + j;
            if (gn >= N) continue;
            float v = acc[i][j] + bias[gn];
            if (RELU) v = fmaxf(v, 0.f);
            stv(&C[(size_t)gm * N + gn], v);
        }
    }
}

// ================= launch =================
extern "C" void kernel_launch(void* const* d_in, const int* in_sizes, int n_in,
                              void* d_out, int out_size, void* d_ws, size_t ws_size,
                              hipStream_t stream) {
    const float* x    = (const float*)d_in[0];
    const int*  src0 = (const int*)d_in[1];
    const int*  dst0 = (const int*)d_in[2];
    const int*  src1 = (const int*)d_in[3];
    const int*  dst1 = (const int*)d_in[4];
    const int*  src2 = (const int*)d_in[5];
    const int*  dst2 = (const int*)d_in[6];
    const float* Ws0 = (const float*)d_in[7];
    const float* Wn0 = (const float*)d_in[8];
    const float* b0  = (const float*)d_in[9];
    const float* Ws1 = (const float*)d_in[10];
    const float* Wn1 = (const float*)d_in[11];
    const float* b1  = (const float*)d_in[12];
    const float* Ws2 = (const float*)d_in[13];
    const float* Wn2 = (const float*)d_in[14];
    const float* b2  = (const float*)d_in[15];
    float* out = (float*)d_out;

    char* RA = (char*)d_ws;            // region A: 61,440,000 B
    char* RB = RA + 61440000;          // region B: 61,440,000 B  (peak 122.88 MB)

    // ----- layer 0 pointers -----
    float* agg0   = (float*)RA;                    // f32 120000x128, live until gemm0
    int* cnt0     = (int*)(RB + 0);                // 480,000
    int* rp0      = (int*)(RB + 480000);           // 480,004 (120001 ints)
    int* cur0     = (int*)(RB + 960004);           // 480,000
    int* col0     = (int*)(RB + 1440004);          // 7,200,000
    int* bsum0    = (int*)(RB + 8640004);          // 512
    bf16* h1      = (bf16*)RB;                     // bf16 120000x256, written by gemm0 (CSR0 dead)

    // ----- layer 1 pointers (region A free after gemm0) -----
    float* agg1   = (float*)(RA + 0);              // 20,480,000
    float* h2     = (float*)(RA + 20480000);       // 20,480,000
    int* cnt1     = (int*)(RA + 40960000);         // 80,000
    int* rp1      = (int*)(RA + 41040000);         // 80,004
    int* cur1     = (int*)(RA + 41120004);         // 80,000
    int* col1     = (int*)(RA + 41200004);         // 800,000
    int* bsum1    = (int*)(RA + 42000004);         // 128

    // ----- layer 2 pointers (region B free after gemm1) -----
    float* agg2   = (float*)(RB + 0);              // 4,096,000
    int* cnt2     = (int*)(RB + 4096000);          // 16,000
    int* rp2      = (int*)(RB + 4112000);          // 16,004
    int* cur2     = (int*)(RB + 4128004);          // 16,000
    int* col2     = (int*)(RB + 4144004);          // 80,000
    int* bsum2    = (int*)(RB + 4224004);          // 16

    // ================= layer 0: 400000 -> 120000, K=128, relu =================
    {
        const int n = N1, E = E0;
        const int B = (n + 1023) / 1024;  // 118
        hipMemsetAsync(cnt0, 0, (size_t)n * 4, stream);
        hist_count<<<(E + 255) / 256, 256, 0, stream>>>(dst0, E, cnt0);
        scan_chunk<<<B, 256, 0, stream>>>(cnt0, n, rp0, bsum0);
        scan_bsum<<<1, 256, 0, stream>>>(bsum0, B, rp0 + n);
        scan_add<<<(n + 255) / 256, 256, 0, stream>>>(rp0, n, bsum0);
        copy_int<<<(n + 255) / 256, 256, 0, stream>>>(rp0, cur0, n);
        csr_fill<<<(E + 255) / 256, 256, 0, stream>>>(src0, dst0, E, cur0, col0);
        gather_mean<D_IN, float><<<(n + 3) / 4, 256, 0, stream>>>(x, rp0, col0, n, agg0);
        dim3 grid((n + 63) / 64, (D_HID + 63) / 64);
        gemm_fused<float, bf16, true><<<grid, 256, 0, stream>>>(x, agg0, Ws0, Wn0, b0, h1, n, D_HID, D_IN);
    }

    // ================= layer 1: 120000 -> 20000, K=256, relu =================
    {
        const int n = N2, E = E1;
        const int B = (n + 1023) / 1024;  // 20
        hipMemsetAsync(cnt1, 0, (size_t)n * 4, stream);
        hist_count<<<(E + 255) / 256, 256, 0, stream>>>(dst1, E, cnt1);
        scan_chunk<<<B, 256, 0, stream>>>(cnt1, n, rp1, bsum1);
        scan_bsum<<<1, 256, 0, stream>>>(bsum1, B, rp1 + n);
        scan_add<<<(n + 255) / 256, 256, 0, stream>>>(rp1, n, bsum1);
        copy_int<<<(n + 255) / 256, 256, 0, stream>>>(rp1, cur1, n);
        csr_fill<<<(E + 255) / 256, 256, 0, stream>>>(src1, dst1, E, cur1, col1);
        gather_mean<D_HID, bf16><<<(n + 3) / 4, 256, 0, stream>>>(h1, rp1, col1, n, agg1);
        dim3 grid((n + 63) / 64, (D_HID + 63) / 64);
        gemm_fused<bf16, float, true><<<grid, 256, 0, stream>>>(h1, agg1, Ws1, Wn1, b1, h2, n, D_HID, D_HID);
    }

    // ================= layer 2: 20000 -> 4000, K=256, no relu =================
    {
        const int n = N3, E = E2;
        const int B = (n + 1023) / 1024;  // 4
        hipMemsetAsync(cnt2, 0, (size_t)n * 4, stream);
        hist_count<<<(E + 255) / 256, 256, 0, stream>>>(dst2, E, cnt2);
        scan_chunk<<<B, 256, 0, stream>>>(cnt2, n, rp2, bsum2);
        scan_bsum<<<1, 256, 0, stream>>>(bsum2, B, rp2 + n);
        scan_add<<<(n + 255) / 256, 256, 0, stream>>>(rp2, n, bsum2);
        copy_int<<<(n + 255) / 256, 256, 0, stream>>>(rp2, cur2, n);
        csr_fill<<<(E + 255) / 256, 256, 0, stream>>>(src2, dst2, E, cur2, col2);
        gather_mean<D_HID, float><<<(n + 3) / 4, 256, 0, stream>>>(h2, rp2, col2, n, agg2);
        dim3 grid((n + 63) / 64, (D_OUT + 63) / 64);
        gemm_fused<float, float, false><<<grid, 256, 0, stream>>>(h2, agg2, Ws2, Wn2, b2, out, n, D_OUT, D_HID);
    }
}

// Round 4
// 852.040 us; speedup vs baseline: 6.5833x; 1.6611x over previous
//
#include <hip/hip_runtime.h>
#include <hip/hip_bf16.h>

typedef __hip_bfloat16 bf16;
typedef __attribute__((ext_vector_type(8))) short short8;
typedef __attribute__((ext_vector_type(4))) float float4v;

// ---- problem constants ----
#define N1 120000
#define N2 20000
#define N3 4000
#define E0 1800000
#define E1 200000
#define E2 20000
#define D_IN 128
#define D_HID 256
#define D_OUT 47

__device__ __forceinline__ void stv(float* p, float v) { *p = v; }
__device__ __forceinline__ void stv(bf16* p, float v) { *p = __float2bfloat16(v); }

__device__ __forceinline__ unsigned short f2bu(float v) {
    union { bf16 h; unsigned short u; } c;
    c.h = __float2bfloat16(v);
    return c.u;
}
__device__ __forceinline__ short f2bs(float v) { return (short)f2bu(v); }

// 8 contiguous elems -> 8 bf16 bit-patterns
__device__ __forceinline__ short8 load8(const bf16* p) {
    union { uint4 u; short8 s; } r;
    r.u = *(const uint4*)p;
    return r.s;
}
__device__ __forceinline__ short8 load8(const float* p) {
    float4 a = *(const float4*)p;
    float4 b = *(const float4*)(p + 4);
    short8 s;
    s[0] = f2bs(a.x); s[1] = f2bs(a.y); s[2] = f2bs(a.z); s[3] = f2bs(a.w);
    s[4] = f2bs(b.x); s[5] = f2bs(b.y); s[6] = f2bs(b.z); s[7] = f2bs(b.w);
    return s;
}

// ================= CSR build =================

__global__ void hist_count(const int* __restrict__ dst, int E, int* __restrict__ cnt) {
    int i = blockIdx.x * blockDim.x + threadIdx.x;
    if (i < E) atomicAdd(&cnt[dst[i]], 1);
}

__global__ __launch_bounds__(256) void scan_chunk(const int* __restrict__ cnt, int n,
                                                  int* __restrict__ out, int* __restrict__ bsum) {
    __shared__ int sd[256];
    int b = blockIdx.x, t = threadIdx.x;
    int base = b * 1024 + t * 4;
    int v[4]; int s = 0;
    #pragma unroll
    for (int j = 0; j < 4; j++) { int i = base + j; v[j] = (i < n) ? cnt[i] : 0; s += v[j]; }
    sd[t] = s;
    __syncthreads();
    for (int off = 1; off < 256; off <<= 1) {
        int x = (t >= off) ? sd[t - off] : 0;
        __syncthreads();
        sd[t] += x;
        __syncthreads();
    }
    int run = sd[t] - s;
    #pragma unroll
    for (int j = 0; j < 4; j++) { int i = base + j; if (i < n) out[i] = run; run += v[j]; }
    if (t == 255) bsum[b] = sd[255];
}

__global__ __launch_bounds__(256) void scan_bsum(int* __restrict__ bsum, int B, int* __restrict__ total) {
    __shared__ int sd[256];
    int t = threadIdx.x;
    int s = (t < B) ? bsum[t] : 0;
    sd[t] = s;
    __syncthreads();
    for (int off = 1; off < 256; off <<= 1) {
        int x = (t >= off) ? sd[t - off] : 0;
        __syncthreads();
        sd[t] += x;
        __syncthreads();
    }
    if (t < B) bsum[t] = sd[t] - s;
    if (t == 255) *total = sd[255];
}

__global__ void scan_add(int* __restrict__ out, int n, const int* __restrict__ bsum) {
    int i = blockIdx.x * blockDim.x + threadIdx.x;
    if (i < n) out[i] += bsum[i >> 10];
}

__global__ void copy_int(const int* __restrict__ a, int* __restrict__ b, int n) {
    int i = blockIdx.x * blockDim.x + threadIdx.x;
    if (i < n) b[i] = a[i];
}

__global__ void csr_fill(const int* __restrict__ src, const int* __restrict__ dst, int E,
                         int* __restrict__ cursor, int* __restrict__ col) {
    int e = blockIdx.x * blockDim.x + threadIdx.x;
    if (e < E) {
        int d = dst[e];
        int p = atomicAdd(&cursor[d], 1);
        col[p] = src[e];
    }
}

// ================= weight transpose + bf16 convert =================
// W[K][N] f32 -> Wt[Npad][K] bf16 (zero-pad n >= N)
__global__ void wt_convert(const float* __restrict__ W, bf16* __restrict__ Wt,
                           int K, int N, int Npad) {
    int i = blockIdx.x * blockDim.x + threadIdx.x;
    if (i >= Npad * K) return;
    int n = i / K, k = i - n * K;
    float v = (n < N) ? W[(size_t)k * N + n] : 0.f;
    Wt[i] = __float2bfloat16(v);
}

// ================= gather-mean (one wave per dst node), bf16 out =================
template <int DIN, typename T>
__global__ __launch_bounds__(256) void gather_mean(const T* __restrict__ h,
        const int* __restrict__ row_ptr, const int* __restrict__ col,
        int n_dst, bf16* __restrict__ agg) {
    int gw = (blockIdx.x * blockDim.x + threadIdx.x) >> 6;
    int lane = threadIdx.x & 63;
    if (gw >= n_dst) return;
    int beg = row_ptr[gw], end = row_ptr[gw + 1];
    constexpr int VP = DIN / 64;  // 2 (f32 d128) or 4 (bf16 d256)
    float s[VP] = {};

    auto accum = [&](int srcn) {
        const T* hp = h + (size_t)srcn * DIN + lane * VP;
        if constexpr (sizeof(T) == 4) {  // float, VP==2
            float2 v = *(const float2*)hp;
            s[0] += v.x; s[1] += v.y;
        } else {  // bf16, VP==4
            union { uint2 u; unsigned short us[4]; } r;
            r.u = *(const uint2*)hp;
            #pragma unroll
            for (int j = 0; j < 4; j++) s[j] += __uint_as_float(((unsigned)r.us[j]) << 16);
        }
    };

    int e = beg;
    for (; e + 1 < end; e += 2) {
        int s0 = col[e], s1 = col[e + 1];
        accum(s0);
        accum(s1);
    }
    if (e < end) accum(col[e]);

    float inv = 1.f / fmaxf((float)(end - beg), 1.f);
    #pragma unroll
    for (int j = 0; j < VP; j++) s[j] *= inv;

    bf16* ap = agg + (size_t)gw * DIN + lane * VP;
    if constexpr (VP == 2) {
        ushort2 o; o.x = f2bu(s[0]); o.y = f2bu(s[1]);
        *(ushort2*)ap = o;
    } else {
        ushort4 o; o.x = f2bu(s[0]); o.y = f2bu(s[1]); o.z = f2bu(s[2]); o.w = f2bu(s[3]);
        *(ushort4*)ap = o;
    }
}

// ================= fused MFMA SAGE GEMM =================
// C[M,Nstore] = relu?( A@Ws + Mn@Wn + b ) as one K-concatenated bf16 MFMA GEMM.
// A: [M][K] (f32 or bf16), Mn: [M][K] bf16, Wst/Wnt: [Npad][K] bf16 (pre-transposed).
// Block tile 128(m) x 64(n), 4 waves of 64x32, 16x16x32 MFMA, BK=32.
template <typename TA, typename TC, bool RELU>
__global__ __launch_bounds__(256) void gemm_mfma(
    const TA* __restrict__ A, const bf16* __restrict__ Mn,
    const bf16* __restrict__ Wst, const bf16* __restrict__ Wnt,
    const float* __restrict__ bias, TC* __restrict__ C,
    int M, int Nstore, int Npad, int K) {
    __shared__ short As[128][48];  // 96B row stride: 16B aligned, uniform banks
    __shared__ short Bs[64][48];

    int tid = threadIdx.x;
    int m0 = blockIdx.x * 128;
    int n0 = blockIdx.y * 64;
    int lane = tid & 63, wid = tid >> 6;
    int wm = (wid & 1) * 64, wn = (wid >> 1) * 32;
    int l15 = lane & 15, quad = lane >> 4;

    float4v acc[4][2] = {};

    int nsteps = (2 * K) >> 5;
    int r = tid >> 2, c = (tid & 3) << 3;
    for (int s = 0; s < nsteps; ++s) {
        int ks = s << 5;
        bool self = ks < K;
        int ko = self ? ks : ks - K;
        // stage A-tile 128x32 (two passes of 64 rows)
        #pragma unroll
        for (int it = 0; it < 2; ++it) {
            int rr = r + it * 64;
            int gm = m0 + rr;
            short8 v = (short8)0;
            if (gm < M) {
                if (self) v = load8(A  + (size_t)gm * K + ko + c);
                else      v = load8(Mn + (size_t)gm * K + ko + c);
            }
            *(short8*)&As[rr][c] = v;
        }
        // stage B-tile 64x32
        {
            int gn = n0 + r;
            short8 w = (short8)0;
            if (gn < Npad) {
                const bf16* Wp = self ? Wst : Wnt;
                w = load8(Wp + (size_t)gn * K + ko + c);
            }
            *(short8*)&Bs[r][c] = w;
        }
        __syncthreads();
        short8 af[4], bfr[2];
        #pragma unroll
        for (int i = 0; i < 4; ++i)
            af[i] = *(const short8*)&As[wm + i * 16 + l15][quad * 8];
        #pragma unroll
        for (int j = 0; j < 2; ++j)
            bfr[j] = *(const short8*)&Bs[wn + j * 16 + l15][quad * 8];
        #pragma unroll
        for (int i = 0; i < 4; ++i)
            #pragma unroll
            for (int j = 0; j < 2; ++j)
                acc[i][j] = __builtin_amdgcn_mfma_f32_16x16x32_bf16(af[i], bfr[j], acc[i][j], 0, 0, 0);
        __syncthreads();
    }

    // epilogue: C/D layout col=lane&15, row=quad*4+reg
    #pragma unroll
    for (int i = 0; i < 4; ++i) {
        #pragma unroll
        for (int j = 0; j < 2; ++j) {
            int gn = n0 + wn + j * 16 + l15;
            if (gn >= Nstore) continue;
            float bv = bias[gn];
            #pragma unroll
            for (int rr = 0; rr < 4; ++rr) {
                int gm = m0 + wm + i * 16 + quad * 4 + rr;
                if (gm >= M) continue;
                float v = acc[i][j][rr] + bv;
                if (RELU) v = fmaxf(v, 0.f);
                stv(&C[(size_t)gm * Nstore + gn], v);
            }
        }
    }
}

// ================= launch =================
extern "C" void kernel_launch(void* const* d_in, const int* in_sizes, int n_in,
                              void* d_out, int out_size, void* d_ws, size_t ws_size,
                              hipStream_t stream) {
    const float* x    = (const float*)d_in[0];
    const int*  src0 = (const int*)d_in[1];
    const int*  dst0 = (const int*)d_in[2];
    const int*  src1 = (const int*)d_in[3];
    const int*  dst1 = (const int*)d_in[4];
    const int*  src2 = (const int*)d_in[5];
    const int*  dst2 = (const int*)d_in[6];
    const float* Ws0 = (const float*)d_in[7];
    const float* Wn0 = (const float*)d_in[8];
    const float* b0  = (const float*)d_in[9];
    const float* Ws1 = (const float*)d_in[10];
    const float* Wn1 = (const float*)d_in[11];
    const float* b1  = (const float*)d_in[12];
    const float* Ws2 = (const float*)d_in[13];
    const float* Wn2 = (const float*)d_in[14];
    const float* b2  = (const float*)d_in[15];
    float* out = (float*)d_out;

    char* RA = (char*)d_ws;            // 61,440,000 B
    char* RB = RA + 61440000;          // 61,440,000 B (total 122.88 MB, proven)

    // persistent bf16 transposed weights (in RA above all layer-1/2 scratch)
    bf16* Wst0 = (bf16*)(RA + 30720000);             // 65,536
    bf16* Wnt0 = (bf16*)(RA + 30785536);             // 65,536
    bf16* Wst1 = (bf16*)(RA + 30851072);             // 131,072
    bf16* Wnt1 = (bf16*)(RA + 30982144);             // 131,072
    bf16* Wst2 = (bf16*)(RA + 31113216);             // 24,576
    bf16* Wnt2 = (bf16*)(RA + 31137792);             // 24,576 (end 31,162,368)

    // layer 0
    bf16* agg0 = (bf16*)RA;                          // 30,720,000
    int* cnt0  = (int*)(RB + 0);                     // 480,000
    int* rp0   = (int*)(RB + 480000);                // 480,004
    int* cur0  = (int*)(RB + 960004);                // 480,000
    int* col0  = (int*)(RB + 1440004);               // 7,200,000
    int* bsum0 = (int*)(RB + 8640004);               // 512
    bf16* h1   = (bf16*)RB;                          // 61,440,000 (CSR0 dead by then)

    // layer 1 (RA reused below weights)
    bf16* agg1 = (bf16*)(RA + 0);                    // 10,240,000
    bf16* h2   = (bf16*)(RA + 10240000);             // 10,240,000
    int* cnt1  = (int*)(RA + 20480000);              // 80,000
    int* rp1   = (int*)(RA + 20560000);              // 80,004
    int* cur1  = (int*)(RA + 20640004);              // 80,000
    int* col1  = (int*)(RA + 20720004);              // 800,000
    int* bsum1 = (int*)(RA + 21520004);              // 512

    // layer 2
    bf16* agg2 = (bf16*)(RA + 21600000);             // 2,048,000
    int* cnt2  = (int*)(RA + 23648000);              // 16,000
    int* rp2   = (int*)(RA + 23664000);              // 16,004
    int* cur2  = (int*)(RA + 23680004);              // 16,000
    int* col2  = (int*)(RA + 23696004);              // 80,000
    int* bsum2 = (int*)(RA + 23776004);              // 64

    // ---- weight conversion (once per launch) ----
    wt_convert<<<(256 * 128 + 255) / 256, 256, 0, stream>>>(Ws0, Wst0, 128, 256, 256);
    wt_convert<<<(256 * 128 + 255) / 256, 256, 0, stream>>>(Wn0, Wnt0, 128, 256, 256);
    wt_convert<<<(256 * 256 + 255) / 256, 256, 0, stream>>>(Ws1, Wst1, 256, 256, 256);
    wt_convert<<<(256 * 256 + 255) / 256, 256, 0, stream>>>(Wn1, Wnt1, 256, 256, 256);
    wt_convert<<<(48 * 256 + 255) / 256, 256, 0, stream>>>(Ws2, Wst2, 256, 47, 48);
    wt_convert<<<(48 * 256 + 255) / 256, 256, 0, stream>>>(Wn2, Wnt2, 256, 47, 48);

    // ================= layer 0: 400000 -> 120000, K=128, relu =================
    {
        const int n = N1, E = E0;
        const int B = (n + 1023) / 1024;
        hipMemsetAsync(cnt0, 0, (size_t)n * 4, stream);
        hist_count<<<(E + 255) / 256, 256, 0, stream>>>(dst0, E, cnt0);
        scan_chunk<<<B, 256, 0, stream>>>(cnt0, n, rp0, bsum0);
        scan_bsum<<<1, 256, 0, stream>>>(bsum0, B, rp0 + n);
        scan_add<<<(n + 255) / 256, 256, 0, stream>>>(rp0, n, bsum0);
        copy_int<<<(n + 255) / 256, 256, 0, stream>>>(rp0, cur0, n);
        csr_fill<<<(E + 255) / 256, 256, 0, stream>>>(src0, dst0, E, cur0, col0);
        gather_mean<D_IN, float><<<(n + 3) / 4, 256, 0, stream>>>(x, rp0, col0, n, agg0);
        dim3 grid((n + 127) / 128, 4);
        gemm_mfma<float, bf16, true><<<grid, 256, 0, stream>>>(x, agg0, Wst0, Wnt0, b0, h1, n, 256, 256, 128);
    }

    // ================= layer 1: 120000 -> 20000, K=256, relu =================
    {
        const int n = N2, E = E1;
        const int B = (n + 1023) / 1024;
        hipMemsetAsync(cnt1, 0, (size_t)n * 4, stream);
        hist_count<<<(E + 255) / 256, 256, 0, stream>>>(dst1, E, cnt1);
        scan_chunk<<<B, 256, 0, stream>>>(cnt1, n, rp1, bsum1);
        scan_bsum<<<1, 256, 0, stream>>>(bsum1, B, rp1 + n);
        scan_add<<<(n + 255) / 256, 256, 0, stream>>>(rp1, n, bsum1);
        copy_int<<<(n + 255) / 256, 256, 0, stream>>>(rp1, cur1, n);
        csr_fill<<<(E + 255) / 256, 256, 0, stream>>>(src1, dst1, E, cur1, col1);
        gather_mean<D_HID, bf16><<<(n + 3) / 4, 256, 0, stream>>>(h1, rp1, col1, n, agg1);
        dim3 grid((n + 127) / 128, 4);
        gemm_mfma<bf16, bf16, true><<<grid, 256, 0, stream>>>(h1, agg1, Wst1, Wnt1, b1, h2, n, 256, 256, 256);
    }

    // ================= layer 2: 20000 -> 4000, K=256, no relu =================
    {
        const int n = N3, E = E2;
        const int B = (n + 1023) / 1024;
        hipMemsetAsync(cnt2, 0, (size_t)n * 4, stream);
        hist_count<<<(E + 255) / 256, 256, 0, stream>>>(dst2, E, cnt2);
        scan_chunk<<<B, 256, 0, stream>>>(cnt2, n, rp2, bsum2);
        scan_bsum<<<1, 256, 0, stream>>>(bsum2, B, rp2 + n);
        scan_add<<<(n + 255) / 256, 256, 0, stream>>>(rp2, n, bsum2);
        copy_int<<<(n + 255) / 256, 256, 0, stream>>>(rp2, cur2, n);
        csr_fill<<<(E + 255) / 256, 256, 0, stream>>>(src2, dst2, E, cur2, col2);
        gather_mean<D_HID, bf16><<<(n + 3) / 4, 256, 0, stream>>>(h2, rp2, col2, n, agg2);
        dim3 grid((n + 127) / 128, 1);
        gemm_mfma<bf16, float, false><<<grid, 256, 0, stream>>>(h2, agg2, Wst2, Wnt2, b2, out, n, 47, 48, 256);
    }
}

// Round 5
// 754.262 us; speedup vs baseline: 7.4367x; 1.1296x over previous
//
#include <hip/hip_runtime.h>
#include <hip/hip_bf16.h>

typedef __hip_bfloat16 bf16;
typedef __attribute__((ext_vector_type(8))) short short8;
typedef __attribute__((ext_vector_type(4))) float float4v;

// ---- problem constants ----
#define N1 120000
#define N2 20000
#define N3 4000
#define E0 1800000
#define E1 200000
#define E2 20000
#define D_IN 128
#define D_HID 256
#define D_OUT 47

__device__ __forceinline__ void stv(float* p, float v) { *p = v; }
__device__ __forceinline__ void stv(bf16* p, float v) { *p = __float2bfloat16(v); }

__device__ __forceinline__ unsigned short f2bu(float v) {
    union { bf16 h; unsigned short u; } c;
    c.h = __float2bfloat16(v);
    return c.u;
}
__device__ __forceinline__ short f2bs(float v) { return (short)f2bu(v); }
__device__ __forceinline__ float bu2f(unsigned short u) { return __uint_as_float(((unsigned)u) << 16); }

__device__ __forceinline__ short8 load8(const bf16* p) {
    union { uint4 u; short8 s; } r;
    r.u = *(const uint4*)p;
    return r.s;
}
__device__ __forceinline__ short8 load8(const float* p) {
    float4 a = *(const float4*)p;
    float4 b = *(const float4*)(p + 4);
    short8 s;
    s[0] = f2bs(a.x); s[1] = f2bs(a.y); s[2] = f2bs(a.z); s[3] = f2bs(a.w);
    s[4] = f2bs(b.x); s[5] = f2bs(b.y); s[6] = f2bs(b.z); s[7] = f2bs(b.w);
    return s;
}

// ================= x -> bf16 conversion =================
__global__ __launch_bounds__(256) void convert_x(const float* __restrict__ x,
                                                 bf16* __restrict__ xb, int n8) {
    int i = blockIdx.x * blockDim.x + threadIdx.x;
    if (i >= n8) return;
    const float* p = x + (size_t)i * 8;
    float4 a = *(const float4*)p;
    float4 b = *(const float4*)(p + 4);
    union { uint4 u; short s[8]; } o;
    o.s[0] = f2bs(a.x); o.s[1] = f2bs(a.y); o.s[2] = f2bs(a.z); o.s[3] = f2bs(a.w);
    o.s[4] = f2bs(b.x); o.s[5] = f2bs(b.y); o.s[6] = f2bs(b.z); o.s[7] = f2bs(b.w);
    *(uint4*)(xb + (size_t)i * 8) = o.u;
}

// ================= batched weight transpose+convert =================
// W[K][N] f32 -> Wt[Npad][K] bf16
__global__ void wt_batch(const float* W0s, const float* W0n, const float* W1s,
                         const float* W1n, const float* W2s, const float* W2n,
                         bf16* T0s, bf16* T0n, bf16* T1s, bf16* T1n, bf16* T2s, bf16* T2n) {
    int i = blockIdx.x * blockDim.x + threadIdx.x;
    const float* W; bf16* T; int K, N, j;
    if      (i <  32768) { W = W0s; T = T0s; K = 128; N = 256; j = i; }
    else if (i <  65536) { W = W0n; T = T0n; K = 128; N = 256; j = i - 32768; }
    else if (i < 131072) { W = W1s; T = T1s; K = 256; N = 256; j = i - 65536; }
    else if (i < 196608) { W = W1n; T = T1n; K = 256; N = 256; j = i - 131072; }
    else if (i < 208896) { W = W2s; T = T2s; K = 256; N = 47;  j = i - 196608; }
    else if (i < 221184) { W = W2n; T = T2n; K = 256; N = 47;  j = i - 208896; }
    else return;
    int n = j / K, k = j - n * K;
    float v = (n < N) ? W[(size_t)k * N + n] : 0.f;
    T[j] = __float2bfloat16(v);
}

// ================= batched CSR build =================
__global__ void hist_batch(const int* __restrict__ d0, const int* __restrict__ d1,
                           const int* __restrict__ d2, int* __restrict__ c0,
                           int* __restrict__ c1, int* __restrict__ c2) {
    int i = blockIdx.x * blockDim.x + threadIdx.x;
    if (i < E0) atomicAdd(&c0[d0[i]], 1);
    else if (i < E0 + E1) atomicAdd(&c1[d1[i - E0]], 1);
    else if (i < E0 + E1 + E2) atomicAdd(&c2[d2[i - E0 - E1]], 1);
}

// chunk=1024; layer chunk counts: 118 / 20 / 4 -> 142 blocks total
__global__ __launch_bounds__(256) void scan_chunk_batch(
    const int* __restrict__ c0, const int* __restrict__ c1, const int* __restrict__ c2,
    int* __restrict__ r0, int* __restrict__ r1, int* __restrict__ r2, int* __restrict__ bsum) {
    __shared__ int sd[256];
    int b = blockIdx.x, t = threadIdx.x;
    const int* cnt; int* out; int* bs; int n, cb;
    if (b < 118)      { cnt = c0; out = r0; bs = bsum;       n = N1; cb = b; }
    else if (b < 138) { cnt = c1; out = r1; bs = bsum + 128; n = N2; cb = b - 118; }
    else              { cnt = c2; out = r2; bs = bsum + 256; n = N3; cb = b - 138; }
    int base = cb * 1024 + t * 4;
    int v[4]; int s = 0;
    #pragma unroll
    for (int j = 0; j < 4; j++) { int i = base + j; v[j] = (i < n) ? cnt[i] : 0; s += v[j]; }
    sd[t] = s;
    __syncthreads();
    for (int off = 1; off < 256; off <<= 1) {
        int x = (t >= off) ? sd[t - off] : 0;
        __syncthreads();
        sd[t] += x;
        __syncthreads();
    }
    int run = sd[t] - s;
    #pragma unroll
    for (int j = 0; j < 4; j++) { int i = base + j; if (i < n) out[i] = run; run += v[j]; }
    if (t == 255) bs[cb] = sd[255];
}

__global__ __launch_bounds__(256) void scan_bsum_batch(int* __restrict__ bsum,
        int* __restrict__ r0, int* __restrict__ r1, int* __restrict__ r2) {
    __shared__ int sd[256];
    int l = blockIdx.x, t = threadIdx.x;
    int B = (l == 0) ? 118 : (l == 1 ? 20 : 4);
    int* bs = bsum + l * 128;
    int s = (t < B) ? bs[t] : 0;
    sd[t] = s;
    __syncthreads();
    for (int off = 1; off < 256; off <<= 1) {
        int x = (t >= off) ? sd[t - off] : 0;
        __syncthreads();
        sd[t] += x;
        __syncthreads();
    }
    if (t < B) bs[t] = sd[t] - s;
    if (t == 255) {
        if (l == 0) r0[N1] = sd[255];
        else if (l == 1) r1[N2] = sd[255];
        else r2[N3] = sd[255];
    }
}

__global__ void scan_add_batch(int* __restrict__ r0, int* __restrict__ r1,
                               int* __restrict__ r2, const int* __restrict__ bsum) {
    int i = blockIdx.x * blockDim.x + threadIdx.x;
    if (i < N1) r0[i] += bsum[i >> 10];
    else if (i < N1 + N2) { int j = i - N1; r1[j] += bsum[128 + (j >> 10)]; }
    else if (i < N1 + N2 + N3) { int j = i - N1 - N2; r2[j] += bsum[256 + (j >> 10)]; }
}

// fills via countdown on cnt: pos = rp[d] + (--cnt[d])
__global__ void csr_fill_batch(const int* __restrict__ s0, const int* __restrict__ d0,
                               const int* __restrict__ s1, const int* __restrict__ d1,
                               const int* __restrict__ s2, const int* __restrict__ d2,
                               int* __restrict__ c0, int* __restrict__ c1, int* __restrict__ c2,
                               const int* __restrict__ r0, const int* __restrict__ r1,
                               const int* __restrict__ r2, int* __restrict__ col0,
                               int* __restrict__ col1, int* __restrict__ col2) {
    int i = blockIdx.x * blockDim.x + threadIdx.x;
    if (i < E0) {
        int d = d0[i];
        col0[r0[d] + atomicSub(&c0[d], 1) - 1] = s0[i];
    } else if (i < E0 + E1) {
        int e = i - E0; int d = d1[e];
        col1[r1[d] + atomicSub(&c1[d], 1) - 1] = s1[e];
    } else if (i < E0 + E1 + E2) {
        int e = i - E0 - E1; int d = d2[e];
        col2[r2[d] + atomicSub(&c2[d], 1) - 1] = s2[e];
    }
}

// ================= gather-mean (one wave per dst node), bf16 out =================
template <int DIN, typename T>
__global__ __launch_bounds__(256) void gather_mean(const T* __restrict__ h,
        const int* __restrict__ rp, const int* __restrict__ col,
        int n_dst, bf16* __restrict__ agg) {
    int gw = (blockIdx.x * blockDim.x + threadIdx.x) >> 6;
    int lane = threadIdx.x & 63;
    if (gw >= n_dst) return;
    int beg = rp[gw], end = rp[gw + 1];
    constexpr int VP = DIN / 64;
    float s[VP] = {};

    auto accum = [&](int srcn) {
        const T* hp = h + (size_t)srcn * DIN + lane * VP;
        if constexpr (sizeof(T) == 4) {  // float, VP==2
            float2 v = *(const float2*)hp;
            s[0] += v.x; s[1] += v.y;
        } else if constexpr (VP == 2) {  // bf16 x2
            union { unsigned u; unsigned short us[2]; } r;
            r.u = *(const unsigned*)hp;
            s[0] += bu2f(r.us[0]); s[1] += bu2f(r.us[1]);
        } else {  // bf16 x4
            union { uint2 u; unsigned short us[4]; } r;
            r.u = *(const uint2*)hp;
            #pragma unroll
            for (int j = 0; j < 4; j++) s[j] += bu2f(r.us[j]);
        }
    };

    int e = beg;
    for (; e + 3 < end; e += 4) {
        int a0 = col[e], a1 = col[e + 1], a2 = col[e + 2], a3 = col[e + 3];
        accum(a0); accum(a1); accum(a2); accum(a3);
    }
    for (; e < end; ++e) accum(col[e]);

    float inv = 1.f / fmaxf((float)(end - beg), 1.f);
    #pragma unroll
    for (int j = 0; j < VP; j++) s[j] *= inv;

    bf16* ap = agg + (size_t)gw * DIN + lane * VP;
    if constexpr (VP == 2) {
        ushort2 o; o.x = f2bu(s[0]); o.y = f2bu(s[1]);
        *(ushort2*)ap = o;
    } else {
        ushort4 o; o.x = f2bu(s[0]); o.y = f2bu(s[1]); o.z = f2bu(s[2]); o.w = f2bu(s[3]);
        *(ushort4*)ap = o;
    }
}

// ================= fused MFMA SAGE GEMM =================
// C[M,Nstore] = relu?( A@Ws + Mn@Wn + b ) as K-concatenated bf16 MFMA GEMM.
// Block tile 128(m) x 128(n), 4 waves of 64x64, 16x16x32 MFMA, BK=32.
template <typename TA, typename TC, bool RELU>
__global__ __launch_bounds__(256) void gemm_mfma(
    const TA* __restrict__ A, const bf16* __restrict__ Mn,
    const bf16* __restrict__ Wst, const bf16* __restrict__ Wnt,
    const float* __restrict__ bias, TC* __restrict__ C,
    int M, int Nstore, int Npad, int K) {
    __shared__ short As[128][48];
    __shared__ short Bs[128][48];

    int tid = threadIdx.x;
    int m0 = blockIdx.x * 128;
    int n0 = blockIdx.y * 128;
    int lane = tid & 63, wid = tid >> 6;
    int wm = (wid & 1) * 64, wn = (wid >> 1) * 64;
    int l15 = lane & 15, quad = lane >> 4;

    float4v acc[4][4] = {};

    int nsteps = (2 * K) >> 5;
    int r = tid >> 2, c = (tid & 3) << 3;
    for (int s = 0; s < nsteps; ++s) {
        int ks = s << 5;
        bool self = ks < K;
        int ko = self ? ks : ks - K;
        #pragma unroll
        for (int it = 0; it < 2; ++it) {
            int rr = r + it * 64;
            // A-tile row
            {
                int gm = m0 + rr;
                short8 v = (short8)0;
                if (gm < M) {
                    if (self) v = load8(A  + (size_t)gm * K + ko + c);
                    else      v = load8(Mn + (size_t)gm * K + ko + c);
                }
                *(short8*)&As[rr][c] = v;
            }
            // B-tile row
            {
                int gn = n0 + rr;
                short8 w = (short8)0;
                if (gn < Npad) {
                    const bf16* Wp = self ? Wst : Wnt;
                    w = load8(Wp + (size_t)gn * K + ko + c);
                }
                *(short8*)&Bs[rr][c] = w;
            }
        }
        __syncthreads();
        short8 af[4], bfr[4];
        #pragma unroll
        for (int i = 0; i < 4; ++i)
            af[i] = *(const short8*)&As[wm + i * 16 + l15][quad * 8];
        #pragma unroll
        for (int j = 0; j < 4; ++j)
            bfr[j] = *(const short8*)&Bs[wn + j * 16 + l15][quad * 8];
        #pragma unroll
        for (int i = 0; i < 4; ++i)
            #pragma unroll
            for (int j = 0; j < 4; ++j)
                acc[i][j] = __builtin_amdgcn_mfma_f32_16x16x32_bf16(af[i], bfr[j], acc[i][j], 0, 0, 0);
        __syncthreads();
    }

    #pragma unroll
    for (int i = 0; i < 4; ++i) {
        #pragma unroll
        for (int j = 0; j < 4; ++j) {
            int gn = n0 + wn + j * 16 + l15;
            if (gn >= Nstore) continue;
            float bv = bias[gn];
            #pragma unroll
            for (int rr = 0; rr < 4; ++rr) {
                int gm = m0 + wm + i * 16 + quad * 4 + rr;
                if (gm >= M) continue;
                float v = acc[i][j][rr] + bv;
                if (RELU) v = fmaxf(v, 0.f);
                stv(&C[(size_t)gm * Nstore + gn], v);
            }
        }
    }
}

// ================= launch =================
extern "C" void kernel_launch(void* const* d_in, const int* in_sizes, int n_in,
                              void* d_out, int out_size, void* d_ws, size_t ws_size,
                              hipStream_t stream) {
    const float* x    = (const float*)d_in[0];
    const int*  src0 = (const int*)d_in[1];
    const int*  dst0 = (const int*)d_in[2];
    const int*  src1 = (const int*)d_in[3];
    const int*  dst1 = (const int*)d_in[4];
    const int*  src2 = (const int*)d_in[5];
    const int*  dst2 = (const int*)d_in[6];
    const float* Ws0 = (const float*)d_in[7];
    const float* Wn0 = (const float*)d_in[8];
    const float* b0  = (const float*)d_in[9];
    const float* Ws1 = (const float*)d_in[10];
    const float* Wn1 = (const float*)d_in[11];
    const float* b1  = (const float*)d_in[12];
    const float* Ws2 = (const float*)d_in[13];
    const float* Wn2 = (const float*)d_in[14];
    const float* b2  = (const float*)d_in[15];
    float* out = (float*)d_out;

    char* W = (char*)d_ws;
    // ---- persistent block (CSR + bsum + weights): [0, 9,676,032) ----
    int* cnt0  = (int*)(W + 0);              // 480,000
    int* cnt1  = (int*)(W + 480000);         //  80,000
    int* cnt2  = (int*)(W + 560000);         //  16,000   (memset [0,576,000) once)
    int* rp0   = (int*)(W + 576000);         // 480,004
    int* rp1   = (int*)(W + 1056004);        //  80,004
    int* rp2   = (int*)(W + 1136008);        //  16,004  (end 1,152,012; pad to 1,152,016)
    int* col0  = (int*)(W + 1152016);        // 7,200,000
    int* col1  = (int*)(W + 8352016);        //   800,000
    int* col2  = (int*)(W + 9152016);        //    80,000
    int* bsum  = (int*)(W + 9232016);        //     1,536 (3 x 128 ints)
    bf16* Wst0 = (bf16*)(W + 9233552);       //    65,536
    bf16* Wnt0 = (bf16*)(W + 9299088);       //    65,536
    bf16* Wst1 = (bf16*)(W + 9364624);       //   131,072
    bf16* Wnt1 = (bf16*)(W + 9495696);       //   131,072
    bf16* Wst2 = (bf16*)(W + 9626768);       //    24,576
    bf16* Wnt2 = (bf16*)(W + 9651344);       //    24,576  (end 9,675,920; pad to 9,676,032)

    const size_t BASE = 9676032;
    const bool use_xb = ws_size >= (size_t)205000000;
    bf16* xb = (bf16*)(W + BASE);                                  // 102,400,000 (use_xb only)
    size_t agg0_off = BASE + (use_xb ? 102400000 : 0);
    bf16* agg0 = (bf16*)(W + agg0_off);                            // 30,720,000
    bf16* h1   = (bf16*)(W + agg0_off + 30720000);                 // 61,440,000
    bf16* agg1 = (bf16*)(W + BASE);                                // 10,240,000 (xb/agg0 dead)
    bf16* h2   = (bf16*)(W + BASE + 10240000);                     // 10,240,000
    bf16* agg2 = (bf16*)(W + BASE + 20480000);                     //  2,048,000

    // ---- phase 1: conversions + batched CSR build ----
    hipMemsetAsync(W, 0, 576000, stream);  // all three cnt arrays
    if (use_xb) {
        int n8 = 400000 * D_IN / 8;  // 6,400,000
        convert_x<<<(n8 + 255) / 256, 256, 0, stream>>>(x, xb, n8);
    }
    wt_batch<<<(221184 + 255) / 256, 256, 0, stream>>>(Ws0, Wn0, Ws1, Wn1, Ws2, Wn2,
                                                       Wst0, Wnt0, Wst1, Wnt1, Wst2, Wnt2);
    const int ETOT = E0 + E1 + E2;
    hist_batch<<<(ETOT + 255) / 256, 256, 0, stream>>>(dst0, dst1, dst2, cnt0, cnt1, cnt2);
    scan_chunk_batch<<<142, 256, 0, stream>>>(cnt0, cnt1, cnt2, rp0, rp1, rp2, bsum);
    scan_bsum_batch<<<3, 256, 0, stream>>>(bsum, rp0, rp1, rp2);
    scan_add_batch<<<(N1 + N2 + N3 + 255) / 256, 256, 0, stream>>>(rp0, rp1, rp2, bsum);
    csr_fill_batch<<<(ETOT + 255) / 256, 256, 0, stream>>>(src0, dst0, src1, dst1, src2, dst2,
                                                           cnt0, cnt1, cnt2, rp0, rp1, rp2,
                                                           col0, col1, col2);

    // ---- layer 0: 400000 -> 120000, K=128, relu ----
    if (use_xb) {
        gather_mean<D_IN, bf16><<<(N1 + 3) / 4, 256, 0, stream>>>(xb, rp0, col0, N1, agg0);
        dim3 grid((N1 + 127) / 128, 2);
        gemm_mfma<bf16, bf16, true><<<grid, 256, 0, stream>>>(xb, agg0, Wst0, Wnt0, b0, h1, N1, 256, 256, 128);
    } else {
        gather_mean<D_IN, float><<<(N1 + 3) / 4, 256, 0, stream>>>(x, rp0, col0, N1, agg0);
        dim3 grid((N1 + 127) / 128, 2);
        gemm_mfma<float, bf16, true><<<grid, 256, 0, stream>>>(x, agg0, Wst0, Wnt0, b0, h1, N1, 256, 256, 128);
    }

    // ---- layer 1: 120000 -> 20000, K=256, relu ----
    gather_mean<D_HID, bf16><<<(N2 + 3) / 4, 256, 0, stream>>>(h1, rp1, col1, N2, agg1);
    {
        dim3 grid((N2 + 127) / 128, 2);
        gemm_mfma<bf16, bf16, true><<<grid, 256, 0, stream>>>(h1, agg1, Wst1, Wnt1, b1, h2, N2, 256, 256, 256);
    }

    // ---- layer 2: 20000 -> 4000, K=256, no relu ----
    gather_mean<D_HID, bf16><<<(N3 + 3) / 4, 256, 0, stream>>>(h2, rp2, col2, N3, agg2);
    {
        dim3 grid((N3 + 127) / 128, 1);
        gemm_mfma<bf16, float, false><<<grid, 256, 0, stream>>>(h2, agg2, Wst2, Wnt2, b2, out, N3, 47, 48, 256);
    }
}